// Round 3
// baseline (99.437 us; speedup 1.0000x reference)
//
#include <hip/hip_runtime.h>

// ---------- types ----------
typedef __attribute__((ext_vector_type(4))) float   float4_;
typedef __attribute__((ext_vector_type(4))) unsigned short ushort4_;
typedef __attribute__((ext_vector_type(8))) __bf16  bf16x8;
typedef __attribute__((ext_vector_type(4))) float   f32x4;

#define NROWS 8192
#define NKEYS 16384
#define DDIM  256

// exp(x/T) == exp2(x * C_SC)
static constexpr float T_INV = (float)(1.0 / 0.07);
static constexpr float C_SC  = (float)(1.0 / (0.07 * 0.6931471805599453));

__device__ __forceinline__ unsigned short f2bf(float x) {
  union { float f; unsigned int u; } v; v.f = x;
  unsigned int r = v.u + 0x7fffu + ((v.u >> 16) & 1u);   // RNE
  return (unsigned short)(r >> 16);
}
__device__ __forceinline__ float bf2f(unsigned short u) {
  union { unsigned int u; float f; } v; v.u = ((unsigned int)u) << 16; return v.f;
}

// ---------------------------------------------------------------------------
// Kernel 1: normalize rows, emit (ALL natural layouts)
//   qs   [8192][256] bf16 : normalized q scaled by C_SC (MFMA A operand)
//   keys [16384][256] bf16: rows 0..8191 = q (unscaled), 8192.. = g (unscaled)
//   Pterm[row]   = dot(q,g)/T (fp32)
//   diagsub[row] = exp2(dot_fp32(qs_bf16, q_bf16))  — bf16-level qq diagonal
// ---------------------------------------------------------------------------
__global__ __launch_bounds__(64) void prep_kernel(
    const float* __restrict__ h, const float* __restrict__ g,
    unsigned short* __restrict__ qs, unsigned short* __restrict__ keys,
    float* __restrict__ Pterm, float* __restrict__ diagsub)
{
  const int row  = blockIdx.x;
  const int lane = threadIdx.x;            // 0..63, 4 dims each
  float4_ hv = *((const float4_*)h + row * 64 + lane);
  float4_ gv = *((const float4_*)g + row * 64 + lane);

  float ssh = hv.x*hv.x + hv.y*hv.y + hv.z*hv.z + hv.w*hv.w;
  float ssg = gv.x*gv.x + gv.y*gv.y + gv.z*gv.z + gv.w*gv.w;
#pragma unroll
  for (int m = 1; m < 64; m <<= 1) {
    ssh += __shfl_xor(ssh, m);
    ssg += __shfl_xor(ssg, m);
  }
  const float sh = 1.0f / fmaxf(sqrtf(ssh), 1e-8f);
  const float sg = 1.0f / fmaxf(sqrtf(ssg), 1e-8f);

  float qn[4] = { hv.x*sh, hv.y*sh, hv.z*sh, hv.w*sh };
  float gn[4] = { gv.x*sg, gv.y*sg, gv.z*sg, gv.w*sg };

  float pd = qn[0]*gn[0] + qn[1]*gn[1] + qn[2]*gn[2] + qn[3]*gn[3];

  unsigned short qb[4], qsb[4], gb[4];
  float dd = 0.0f;
#pragma unroll
  for (int j = 0; j < 4; ++j) {
    qb[j]  = f2bf(qn[j]);
    qsb[j] = f2bf(qn[j] * C_SC);
    gb[j]  = f2bf(gn[j]);
    dd += bf2f(qsb[j]) * bf2f(qb[j]);
  }
#pragma unroll
  for (int m = 1; m < 64; m <<= 1) {
    pd += __shfl_xor(pd, m);
    dd += __shfl_xor(dd, m);
  }

  ushort4_ vqs = { qsb[0], qsb[1], qsb[2], qsb[3] };
  ushort4_ vq  = { qb[0],  qb[1],  qb[2],  qb[3]  };
  ushort4_ vg  = { gb[0],  gb[1],  gb[2],  gb[3]  };
  *((ushort4_*)qs   + (size_t)row * 64 + lane)           = vqs;
  *((ushort4_*)keys + (size_t)row * 64 + lane)           = vq;
  *((ushort4_*)keys + (size_t)(NROWS + row) * 64 + lane) = vg;

  if (lane == 0) {
    Pterm[row]   = pd * T_INV;
    diagsub[row] = __builtin_amdgcn_exp2f(dd);
  }
}

// ---------------------------------------------------------------------------
// Kernel 2: fused GEMM + exp2 + row-sum.
// Grid 256 = 64 M-tiles (BM=128) x 4 key-slices (4096 keys).
// slice = bid & 3  -> each XCD (bid % 8) sees ONE fixed slice (L2-resident).
// 8 waves (2m x 4n); Q frags in registers; keys reg-staged into double-
// buffered LDS (64 keys/chunk) with XOR swizzle applied at ds_write and
// undone at ds_read through the SAME lds_off() — consistent by construction.
// ---------------------------------------------------------------------------
__device__ __forceinline__ int lds_off(int r, int g) {   // elements
  return r * DDIM + (((g ^ (r & 7)) & 31) << 3);
}

__global__ __launch_bounds__(512, 2) void nce_gemm(
    const unsigned short* __restrict__ qs,
    const unsigned short* __restrict__ keys,
    float* __restrict__ S)
{
  __shared__ __align__(16) unsigned short lds_k[2 * 64 * DDIM]; // 64 KB

  const int tid  = threadIdx.x;
  const int wid  = tid >> 6;
  const int lane = tid & 63;
  const int l15  = lane & 15, l4 = lane >> 4;

  const int bid   = blockIdx.x;
  const int slice = bid & 3;               // constant per XCD
  const int mtile = bid >> 2;              // 0..63

  const int wm = wid >> 2;                 // 0..1
  const int wn = wid & 3;                  // 0..3
  const int m0 = mtile * 128 + wm * 64;

  // ---- Q fragments into registers (natural layout, pre-scaled by C_SC) ----
  bf16x8 a[4][8];
#pragma unroll
  for (int mf = 0; mf < 4; ++mf) {
    const unsigned short* rp = qs + (size_t)(m0 + mf * 16 + l15) * DDIM + l4 * 8;
#pragma unroll
    for (int kk = 0; kk < 8; ++kk)
      a[mf][kk] = *(const bf16x8*)(rp + kk * 32);
  }

  const f32x4 zero4 = { 0.f, 0.f, 0.f, 0.f };
  f32x4 acc[4] = { zero4, zero4, zero4, zero4 };
  float Sp[4][4] = {};

  // staging map: thread t -> key-row sr = t>>3, groups (t&7)+8u, u=0..3
  const int sr  = tid >> 3;                // 0..63
  const int sg0 = tid & 7;
  const unsigned short* kslice = keys + (size_t)slice * 4096 * DDIM;

  bf16x8 stg[4];
  auto load_chunk = [&](int c) {
    const unsigned short* base = kslice + ((size_t)c * 64 + sr) * DDIM;
#pragma unroll
    for (int u = 0; u < 4; ++u)
      stg[u] = *(const bf16x8*)(base + ((sg0 + 8 * u) << 3));
  };
  auto write_chunk = [&](int buf) {
    unsigned short* dst = lds_k + buf * (64 * DDIM);
#pragma unroll
    for (int u = 0; u < 4; ++u)
      *(bf16x8*)(dst + lds_off(sr, sg0 + 8 * u)) = stg[u];
  };

  load_chunk(0);
  for (int c = 0; c < 64; ++c) {
    const int buf = c & 1;
    write_chunk(buf);
    __syncthreads();                       // LDS writes visible; dbuf-safe
    if (c + 1 < 64) load_chunk(c + 1);     // overlap HBM/L2 latency w/ MFMA

    const unsigned short* lb = lds_k + buf * (64 * DDIM);
#pragma unroll
    for (int kk = 0; kk < 8; ++kk) {
      bf16x8 b = *(const bf16x8*)(lb + lds_off(wn * 16 + l15, kk * 4 + l4));
#pragma unroll
      for (int mf = 0; mf < 4; ++mf)
        acc[mf] = __builtin_amdgcn_mfma_f32_16x16x32_bf16(a[mf][kk], b, acc[mf], 0, 0, 0);
    }
    // harvest: D layout (m89): col = lane&15, row = (lane>>4)*4 + reg
#pragma unroll
    for (int mf = 0; mf < 4; ++mf)
#pragma unroll
      for (int q = 0; q < 4; ++q) {
        Sp[mf][q] += __builtin_amdgcn_exp2f(acc[mf][q]);
        acc[mf][q] = 0.0f;
      }
  }

  // reduce across the 16 columns (lanes sharing l4), then one atomic/row
#pragma unroll
  for (int mf = 0; mf < 4; ++mf)
#pragma unroll
    for (int q = 0; q < 4; ++q) {
      float v = Sp[mf][q];
      v += __shfl_xor(v, 1); v += __shfl_xor(v, 2);
      v += __shfl_xor(v, 4); v += __shfl_xor(v, 8);
      Sp[mf][q] = v;
    }
  if (l15 == 0) {
#pragma unroll
    for (int mf = 0; mf < 4; ++mf)
#pragma unroll
      for (int q = 0; q < 4; ++q)
        atomicAdd(&S[m0 + mf * 16 + l4 * 4 + q], Sp[mf][q]);
  }
}

// ---------------------------------------------------------------------------
// Kernel 3: loss = mean_i [ log(S_i - diagsub_i) - Pterm_i ]
// (clamped so a residual bug yields finite diagnostic output, not NaN)
// ---------------------------------------------------------------------------
__global__ __launch_bounds__(256) void finalize_kernel(
    const float* __restrict__ S, const float* __restrict__ Pterm,
    const float* __restrict__ diagsub, float* __restrict__ out)
{
  const int tid = threadIdx.x;
  float acc = 0.0f;
  for (int i = tid; i < NROWS; i += 256) {
    float v = S[i] - diagsub[i];
    acc += logf(fmaxf(v, 1e-20f)) - Pterm[i];
  }
#pragma unroll
  for (int m = 1; m < 64; m <<= 1) acc += __shfl_xor(acc, m);
  __shared__ float w[4];
  if ((tid & 63) == 0) w[tid >> 6] = acc;
  __syncthreads();
  if (tid == 0) out[0] = (w[0] + w[1] + w[2] + w[3]) * (1.0f / (float)NROWS);
}

// ---------------------------------------------------------------------------
extern "C" void kernel_launch(void* const* d_in, const int* in_sizes, int n_in,
                              void* d_out, int out_size, void* d_ws, size_t ws_size,
                              hipStream_t stream) {
  const float* h  = (const float*)d_in[0];
  const float* hg = (const float*)d_in[1];

  char* ws = (char*)d_ws;
  const size_t OFF_QS   = 0;                      // 4 MB
  const size_t OFF_KEYS = (size_t)4 << 20;        // 8 MB
  const size_t OFF_P    = (size_t)12 << 20;       // 32 KB
  const size_t OFF_DIAG = OFF_P + 32 * 1024;      // 32 KB
  const size_t OFF_S    = OFF_DIAG + 32 * 1024;   // 32 KB
  const size_t NEED     = OFF_S + 32 * 1024;
  if (ws_size < NEED) return;

  unsigned short* qs   = (unsigned short*)(ws + OFF_QS);
  unsigned short* keys = (unsigned short*)(ws + OFF_KEYS);
  float* Pterm   = (float*)(ws + OFF_P);
  float* diagsub = (float*)(ws + OFF_DIAG);
  float* S       = (float*)(ws + OFF_S);

  hipMemsetAsync(S, 0, NROWS * sizeof(float), stream);
  prep_kernel<<<NROWS, 64, 0, stream>>>(h, hg, qs, keys, Pterm, diagsub);
  nce_gemm<<<256, 512, 0, stream>>>(qs, keys, S);
  finalize_kernel<<<1, 256, 0, stream>>>(S, Pterm, diagsub, (float*)d_out);
}